// Round 7
// baseline (155.359 us; speedup 1.0000x reference)
//
#include <hip/hip_runtime.h>
#include <hip/hip_bf16.h>
#include <cstdint>

#define HDIM 1024
#define NT 32   // K-tiles of 32

typedef __attribute__((ext_vector_type(8))) __bf16 bf16x8;
typedef __attribute__((ext_vector_type(8))) unsigned short u16x8;
typedef __attribute__((ext_vector_type(4))) float f32x4;

static __device__ __forceinline__ unsigned short f2b(float f) {
    __hip_bfloat16 h = __float2bfloat16(f);
    return __builtin_bit_cast(unsigned short, h);
}
static __device__ __forceinline__ float b2f(unsigned short u) {
    unsigned int w = ((unsigned int)u) << 16;
    return __builtin_bit_cast(float, w);
}

static __device__ __forceinline__ void barrier_fence() {
    asm volatile("" ::: "memory");
    __builtin_amdgcn_s_barrier();
    asm volatile("" ::: "memory");
}

// fp32 -> bf16 pack: weights + x,h (row-major), 44 MB in ws
__global__ void __launch_bounds__(256) cvt_all(
    const float* __restrict__ x, const float* __restrict__ h,
    const float* __restrict__ wih, const float* __restrict__ ur,
    const float* __restrict__ uz, const float* __restrict__ un,
    unsigned short* __restrict__ wb, unsigned short* __restrict__ urb,
    unsigned short* __restrict__ uzb, unsigned short* __restrict__ unb,
    unsigned short* __restrict__ xb, unsigned short* __restrict__ hb) {
    int b = blockIdx.x;
    const float* src; unsigned short* dst; int idx;
    if (b < 3072)       { src = wih; dst = wb;  idx = b; }
    else if (b < 4096)  { src = ur;  dst = urb; idx = b - 3072; }
    else if (b < 5120)  { src = uz;  dst = uzb; idx = b - 4096; }
    else if (b < 6144)  { src = un;  dst = unb; idx = b - 5120; }
    else if (b < 14336) { src = x;   dst = xb;  idx = b - 6144; }
    else                { src = h;   dst = hb;  idx = b - 14336; }
    int i = idx * 256 + threadIdx.x;
    float4 v = ((const float4*)src)[i];
    ushort4 o;
    o.x = f2b(v.x); o.y = f2b(v.y); o.z = f2b(v.z); o.w = f2b(v.w);
    ((ushort4*)dst)[i] = o;
}

// R2 skeleton (4 waves, BM=128, BN=64, 2 blocks/CU, 2-barrier dbuf) with:
//  - corrected counted wait vmcnt(14): drains exactly the PREVIOUS tile's
//    loads, leaves all 14 just-issued loads in flight across COMPUTE
//  - panel-major XCD swizzle: each XCD owns 2 N-panels -> weight panel
//    (768 KB) stays L2-resident for its 64 resident blocks
//  - epilogue h read as bf16 (halves the h re-read traffic)
// LDS per buffer (ushort): xs[0,4096) hs[4096,8192) w[mi]@8192+mi*2048.
// Swizzle: 16B slot s of row r at s ^ ((r>>1)&3), both sides (conflict-free).
__global__ void __launch_bounds__(256, 2)
gru7(const unsigned short* __restrict__ xb, const unsigned short* __restrict__ hb,
     const unsigned short* __restrict__ wih,
     const unsigned short* __restrict__ ur,
     const unsigned short* __restrict__ uz,
     const unsigned short* __restrict__ un,
     const float* __restrict__ bih, const float* __restrict__ bun,
     float* __restrict__ out) {
    __shared__ __align__(16) unsigned short smem[2][20480];

    const int tid  = threadIdx.x;
    const int lane = tid & 63;
    const int wv   = tid >> 6;
    const int wm   = wv >> 1;
    const int wn   = wv & 1;
    const int lr   = lane & 15;
    const int ls   = lane >> 4;

    // panel-major XCD swizzle: 1024 blocks; xcd = bid&7 (dispatch round-robin);
    // each XCD covers panels {2*xcd, 2*xcd+1} sweeping all 64 M-rows.
    const int bid   = blockIdx.x;
    const int xcd   = bid & 7;
    const int loc   = bid >> 3;              // 0..127
    const int panel = xcd * 2 + (loc >> 6);  // 0..15
    const int m0    = (loc & 63) * 128;
    const int n0    = panel * 64;

    const unsigned short* wb6[6] = {
        wih + (size_t)n0 * HDIM,
        wih + (size_t)(HDIM + n0) * HDIM,
        wih + (size_t)(2 * HDIM + n0) * HDIM,
        ur  + (size_t)n0 * HDIM,
        uz  + (size_t)n0 * HDIM,
        un  + (size_t)n0 * HDIM
    };

    // staging chunk indices (weights): chunk c covers row c>>2, swizzled source slot
    const int wr  = tid >> 2;
    const int wsl = (tid & 3) ^ ((tid >> 3) & 3);

    f32x4 acc[4][4][2];
#pragma unroll
    for (int g = 0; g < 4; ++g)
#pragma unroll
        for (int mf = 0; mf < 4; ++mf)
#pragma unroll
            for (int nf = 0; nf < 2; ++nf)
                acc[g][mf][nf] = f32x4{0.f, 0.f, 0.f, 0.f};

    auto STAGE = [&](int bufi, int kt) {
        const int k0 = kt * 32;
        unsigned short* sb = &smem[bufi][0];
        // 6 weight tiles via global_load_lds w16 (linear LDS dest, pre-swizzled src)
#pragma unroll
        for (int mi = 0; mi < 6; ++mi) {
            const unsigned short* g = wb6[mi] + (size_t)wr * HDIM + k0 + wsl * 8;
            __builtin_amdgcn_global_load_lds(
                (const __attribute__((address_space(1))) void*)g,
                (__attribute__((address_space(3))) void*)(sb + 8192 + mi * 2048 + wv * 512),
                16, 0, 0);
        }
        // x/h bf16 tiles (8 loads/thread)
#pragma unroll
        for (int half = 0; half < 2; ++half) {
            const int c2 = half * 256 + tid;
            const int r2 = c2 >> 2;
            const int sl = (c2 & 3) ^ ((c2 >> 3) & 3);
            const unsigned short* gx = xb + (size_t)(m0 + r2) * HDIM + k0 + sl * 8;
            const unsigned short* gh = hb + (size_t)(m0 + r2) * HDIM + k0 + sl * 8;
            __builtin_amdgcn_global_load_lds(
                (const __attribute__((address_space(1))) void*)gx,
                (__attribute__((address_space(3))) void*)(sb + half * 2048 + wv * 512),
                16, 0, 0);
            __builtin_amdgcn_global_load_lds(
                (const __attribute__((address_space(1))) void*)gh,
                (__attribute__((address_space(3))) void*)(sb + 4096 + half * 2048 + wv * 512),
                16, 0, 0);
        }
    };

    auto COMPUTE = [&](int bufi) {
        const unsigned short* sb = &smem[bufi][0];
        const int sel = (lr >> 1) & 3;
        const int fo  = (ls ^ sel) << 3;
        bf16x8 ax[4], ah[4];
#pragma unroll
        for (int mf = 0; mf < 4; ++mf) {
            const int row = wm * 64 + mf * 16 + lr;
            ax[mf] = *(const bf16x8*)(sb + row * 32 + fo);
            ah[mf] = *(const bf16x8*)(sb + 4096 + row * 32 + fo);
        }
#pragma unroll
        for (int mi = 0; mi < 6; ++mi) {
            const unsigned short* wt = sb + 8192 + mi * 2048;
            bf16x8 b0 = *(const bf16x8*)(wt + (wn * 32 + lr) * 32 + fo);
            bf16x8 b1 = *(const bf16x8*)(wt + (wn * 32 + 16 + lr) * 32 + fo);
            const int g = (mi == 0 || mi == 3) ? 0 : (mi == 1 || mi == 4) ? 1 : (mi == 2) ? 2 : 3;
            const bf16x8* a = (mi < 3) ? ax : ah;
#pragma unroll
            for (int mf = 0; mf < 4; ++mf) {
                acc[g][mf][0] = __builtin_amdgcn_mfma_f32_16x16x32_bf16(a[mf], b0, acc[g][mf][0], 0, 0, 0);
                acc[g][mf][1] = __builtin_amdgcn_mfma_f32_16x16x32_bf16(a[mf], b1, acc[g][mf][1], 0, 0, 0);
            }
        }
    };

    // counted wait: 14 loads/STAGE -> vmcnt(14) drains exactly the previous
    // tile's stragglers and leaves ALL 14 fresh loads in flight.
    auto WAITN = [&]() { asm volatile("s_waitcnt vmcnt(14)" ::: "memory"); };

    STAGE(0, 0);
#pragma unroll 1
    for (int kt = 0; kt < NT - 2; kt += 2) {
        STAGE(1, kt + 1); WAITN(); barrier_fence();
        COMPUTE(0);       barrier_fence();
        STAGE(0, kt + 2); WAITN(); barrier_fence();
        COMPUTE(1);       barrier_fence();
    }
    STAGE(1, NT - 1); WAITN(); barrier_fence();
    COMPUTE(0);       barrier_fence();
    asm volatile("s_waitcnt vmcnt(0) lgkmcnt(0)" ::: "memory");
    __builtin_amdgcn_s_barrier();
    asm volatile("" ::: "memory");
    COMPUTE(1);

    // epilogue: gates + output (C/D layout: col=lane&15, row=(lane>>4)*4+reg)
#pragma unroll
    for (int nf = 0; nf < 2; ++nf) {
        const int gc = n0 + wn * 32 + nf * 16 + lr;
        const float br  = bih[gc];
        const float bz  = bih[HDIM + gc];
        const float bnx = bih[2 * HDIM + gc];
        const float bn2 = bun[gc];
#pragma unroll
        for (int mf = 0; mf < 4; ++mf) {
#pragma unroll
            for (int rr = 0; rr < 4; ++rr) {
                const int gr = m0 + wm * 64 + mf * 16 + ls * 4 + rr;
                const float rv = 1.f / (1.f + __expf(-(acc[0][mf][nf][rr] + br)));
                const float zv = 1.f / (1.f + __expf(-(acc[1][mf][nf][rr] + bz)));
                const float nv = tanhf(acc[2][mf][nf][rr] + bnx + rv * (acc[3][mf][nf][rr] + bn2));
                const float hv = b2f(hb[(size_t)gr * HDIM + gc]);
                out[(size_t)gr * HDIM + gc] = (1.f - zv) * nv + zv * hv;
            }
        }
    }
}

// ---------- fallback (ws too small): R2's proven 4-wave fp32-staging kernel ----------
__global__ void __launch_bounds__(256, 2)
gru_fused_fb(const float* __restrict__ hg,
             const float* __restrict__ xg32, const float* __restrict__ hg32,
             const unsigned short* __restrict__ wih,
             const unsigned short* __restrict__ ur,
             const unsigned short* __restrict__ uz,
             const unsigned short* __restrict__ un,
             const float* __restrict__ bih, const float* __restrict__ bun,
             float* __restrict__ out) {
    __shared__ __align__(16) unsigned short smem[2][20480];
    const int tid  = threadIdx.x;
    const int lane = tid & 63;
    const int wv   = tid >> 6;
    const int wm   = wv >> 1;
    const int wn   = wv & 1;
    const int lr   = lane & 15;
    const int ls   = lane >> 4;
    const int m0   = blockIdx.y * 128;
    const int n0   = blockIdx.x * 64;

    const unsigned short* wb6[6] = {
        wih + (size_t)n0 * HDIM, wih + (size_t)(HDIM + n0) * HDIM,
        wih + (size_t)(2 * HDIM + n0) * HDIM, ur + (size_t)n0 * HDIM,
        uz + (size_t)n0 * HDIM, un + (size_t)n0 * HDIM
    };
    const int wr  = tid >> 2;
    const int wsl = (tid & 3) ^ ((tid >> 3) & 3);

    f32x4 acc[4][4][2];
#pragma unroll
    for (int g = 0; g < 4; ++g)
#pragma unroll
        for (int mf = 0; mf < 4; ++mf)
#pragma unroll
            for (int nf = 0; nf < 2; ++nf)
                acc[g][mf][nf] = f32x4{0.f, 0.f, 0.f, 0.f};

    auto STAGE = [&](int bufi, int kt) {
        const int k0 = kt * 32;
        unsigned short* sb = &smem[bufi][0];
        float4 fx[2][2], fh[2][2];
#pragma unroll
        for (int half = 0; half < 2; ++half) {
            const int c2 = half * 256 + tid;
            const int r2 = c2 >> 2;
            const int sl = c2 & 3;
            const float* gx = xg32 + (size_t)(m0 + r2) * HDIM + k0 + sl * 8;
            const float* gh = hg32 + (size_t)(m0 + r2) * HDIM + k0 + sl * 8;
            fx[half][0] = ((const float4*)gx)[0];
            fx[half][1] = ((const float4*)gx)[1];
            fh[half][0] = ((const float4*)gh)[0];
            fh[half][1] = ((const float4*)gh)[1];
        }
#pragma unroll
        for (int mi = 0; mi < 6; ++mi) {
            const unsigned short* g = wb6[mi] + (size_t)wr * HDIM + k0 + wsl * 8;
            __builtin_amdgcn_global_load_lds(
                (const __attribute__((address_space(1))) void*)g,
                (__attribute__((address_space(3))) void*)(sb + 8192 + mi * 2048 + wv * 512),
                16, 0, 0);
        }
#pragma unroll
        for (int half = 0; half < 2; ++half) {
            const int c2 = half * 256 + tid;
            const int r2 = c2 >> 2;
            const int sp = (c2 & 3) ^ ((c2 >> 3) & 3);
            u16x8 px, ph;
#pragma unroll
            for (int q = 0; q < 4; ++q) {
                px[q]     = f2b(fx[half][0][q]);
                px[q + 4] = f2b(fx[half][1][q]);
                ph[q]     = f2b(fh[half][0][q]);
                ph[q + 4] = f2b(fh[half][1][q]);
            }
            *(u16x8*)(sb + r2 * 32 + sp * 8)        = px;
            *(u16x8*)(sb + 4096 + r2 * 32 + sp * 8) = ph;
        }
    };
    auto COMPUTE = [&](int bufi) {
        const unsigned short* sb = &smem[bufi][0];
        const int sel = (lr >> 1) & 3;
        const int fo  = (ls ^ sel) << 3;
        bf16x8 ax[4], ah[4];
#pragma unroll
        for (int mf = 0; mf < 4; ++mf) {
            const int row = wm * 64 + mf * 16 + lr;
            ax[mf] = *(const bf16x8*)(sb + row * 32 + fo);
            ah[mf] = *(const bf16x8*)(sb + 4096 + row * 32 + fo);
        }
#pragma unroll
        for (int mi = 0; mi < 6; ++mi) {
            const unsigned short* wt = sb + 8192 + mi * 2048;
            bf16x8 b0 = *(const bf16x8*)(wt + (wn * 32 + lr) * 32 + fo);
            bf16x8 b1 = *(const bf16x8*)(wt + (wn * 32 + 16 + lr) * 32 + fo);
            const int g = (mi == 0 || mi == 3) ? 0 : (mi == 1 || mi == 4) ? 1 : (mi == 2) ? 2 : 3;
            const bf16x8* a = (mi < 3) ? ax : ah;
#pragma unroll
            for (int mf = 0; mf < 4; ++mf) {
                acc[g][mf][0] = __builtin_amdgcn_mfma_f32_16x16x32_bf16(a[mf], b0, acc[g][mf][0], 0, 0, 0);
                acc[g][mf][1] = __builtin_amdgcn_mfma_f32_16x16x32_bf16(a[mf], b1, acc[g][mf][1], 0, 0, 0);
            }
        }
    };
    auto WAITN = [&]() { asm volatile("s_waitcnt vmcnt(6) lgkmcnt(0)" ::: "memory"); };

    STAGE(0, 0);
#pragma unroll 1
    for (int kt = 0; kt < NT - 2; kt += 2) {
        STAGE(1, kt + 1); WAITN(); barrier_fence();
        COMPUTE(0);       barrier_fence();
        STAGE(0, kt + 2); WAITN(); barrier_fence();
        COMPUTE(1);       barrier_fence();
    }
    STAGE(1, NT - 1); WAITN(); barrier_fence();
    COMPUTE(0);       barrier_fence();
    asm volatile("s_waitcnt vmcnt(0) lgkmcnt(0)" ::: "memory");
    __builtin_amdgcn_s_barrier();
    asm volatile("" ::: "memory");
    COMPUTE(1);

#pragma unroll
    for (int nf = 0; nf < 2; ++nf) {
        const int gc = n0 + wn * 32 + nf * 16 + lr;
        const float br  = bih[gc];
        const float bz  = bih[HDIM + gc];
        const float bnx = bih[2 * HDIM + gc];
        const float bn2 = bun[gc];
#pragma unroll
        for (int mf = 0; mf < 4; ++mf) {
#pragma unroll
            for (int rr = 0; rr < 4; ++rr) {
                const int gr = m0 + wm * 64 + mf * 16 + ls * 4 + rr;
                const float rv = 1.f / (1.f + __expf(-(acc[0][mf][nf][rr] + br)));
                const float zv = 1.f / (1.f + __expf(-(acc[1][mf][nf][rr] + bz)));
                const float nv = tanhf(acc[2][mf][nf][rr] + bnx + rv * (acc[3][mf][nf][rr] + bn2));
                const float hv = hg[(size_t)gr * HDIM + gc];
                out[(size_t)gr * HDIM + gc] = (1.f - zv) * nv + zv * hv;
            }
        }
    }
}

extern "C" void kernel_launch(void* const* d_in, const int* in_sizes, int n_in,
                              void* d_out, int out_size, void* d_ws, size_t ws_size,
                              hipStream_t stream) {
    const float* x   = (const float*)d_in[0];
    const float* h   = (const float*)d_in[1];
    const float* Wih = (const float*)d_in[2];
    const float* bih = (const float*)d_in[3];
    const float* Ur  = (const float*)d_in[4];
    const float* Uz  = (const float*)d_in[5];
    const float* Un  = (const float*)d_in[6];
    const float* bun = (const float*)d_in[7];
    float* out = (float*)d_out;

    unsigned short* wsp  = (unsigned short*)d_ws;
    unsigned short* wihb = wsp;
    unsigned short* urb  = wihb + 3 * 1024 * 1024;
    unsigned short* uzb  = urb + 1024 * 1024;
    unsigned short* unb  = uzb + 1024 * 1024;
    unsigned short* xbb  = unb + 1024 * 1024;
    unsigned short* hbb  = xbb + 8 * 1024 * 1024;

    const bool big = ws_size >= 46137344ull;  // 44 MB

    cvt_all<<<big ? 22528 : 6144, 256, 0, stream>>>(
        x, h, Wih, Ur, Uz, Un, wihb, urb, uzb, unb, xbb, hbb);

    if (big) {
        gru7<<<1024, 256, 0, stream>>>(
            xbb, hbb, wihb, urb, uzb, unb, bih, bun, out);
    } else {
        dim3 grid(HDIM / 64, 8192 / 128);
        gru_fused_fb<<<grid, 256, 0, stream>>>(
            h, x, h, wihb, urb, uzb, unb, bih, bun, out);
    }
}

// Round 8
// 144.211 us; speedup vs baseline: 1.0773x; 1.0773x over previous
//
#include <hip/hip_runtime.h>
#include <hip/hip_bf16.h>
#include <cstdint>

#define HDIM 1024
#define NT 32   // K-tiles of 32

typedef __attribute__((ext_vector_type(8))) __bf16 bf16x8;
typedef __attribute__((ext_vector_type(8))) unsigned short u16x8;
typedef __attribute__((ext_vector_type(4))) float f32x4;

static __device__ __forceinline__ unsigned short f2b(float f) {
    __hip_bfloat16 h = __float2bfloat16(f);
    return __builtin_bit_cast(unsigned short, h);
}
static __device__ __forceinline__ float b2f(unsigned short u) {
    unsigned int w = ((unsigned int)u) << 16;
    return __builtin_bit_cast(float, w);
}

static __device__ __forceinline__ void barrier_fence() {
    asm volatile("" ::: "memory");
    __builtin_amdgcn_s_barrier();
    asm volatile("" ::: "memory");
}

// fp32 -> bf16 pack: weights + x,h (row-major), 44 MB in ws
__global__ void __launch_bounds__(256) cvt_all(
    const float* __restrict__ x, const float* __restrict__ h,
    const float* __restrict__ wih, const float* __restrict__ ur,
    const float* __restrict__ uz, const float* __restrict__ un,
    unsigned short* __restrict__ wb, unsigned short* __restrict__ urb,
    unsigned short* __restrict__ uzb, unsigned short* __restrict__ unb,
    unsigned short* __restrict__ xb, unsigned short* __restrict__ hb) {
    int b = blockIdx.x;
    const float* src; unsigned short* dst; int idx;
    if (b < 3072)       { src = wih; dst = wb;  idx = b; }
    else if (b < 4096)  { src = ur;  dst = urb; idx = b - 3072; }
    else if (b < 5120)  { src = uz;  dst = uzb; idx = b - 4096; }
    else if (b < 6144)  { src = un;  dst = unb; idx = b - 5120; }
    else if (b < 14336) { src = x;   dst = xb;  idx = b - 6144; }
    else                { src = h;   dst = hb;  idx = b - 14336; }
    int i = idx * 256 + threadIdx.x;
    float4 v = ((const float4*)src)[i];
    ushort4 o;
    o.x = f2b(v.x); o.y = f2b(v.y); o.z = f2b(v.z); o.w = f2b(v.w);
    ((ushort4*)dst)[i] = o;
}

// R2 skeleton (4 waves, BM=128, BN=64, 2 blocks/CU, 2-barrier dbuf),
// natural 2D grid (x-major: 16 n-panels of one m-row dispatch consecutively
// -> x/h row-panel L2/L3-hot, 12 MB weights fit aggregate L2), with:
//  - EXACT counted wait vmcnt(10): 10 loads/STAGE; drains precisely the
//    previous buffer's 10 loads, keeps all 10 fresh loads in flight
//  - epilogue h read as bf16
// LDS per buffer (ushort): xs[0,4096) hs[4096,8192) w[mi]@8192+mi*2048.
// Swizzle: 16B slot s of row r at s ^ ((r>>1)&3), both sides (conflict-free).
__global__ void __launch_bounds__(256, 2)
gru8(const unsigned short* __restrict__ xb, const unsigned short* __restrict__ hb,
     const unsigned short* __restrict__ wih,
     const unsigned short* __restrict__ ur,
     const unsigned short* __restrict__ uz,
     const unsigned short* __restrict__ un,
     const float* __restrict__ bih, const float* __restrict__ bun,
     float* __restrict__ out) {
    __shared__ __align__(16) unsigned short smem[2][20480];

    const int tid  = threadIdx.x;
    const int lane = tid & 63;
    const int wv   = tid >> 6;
    const int wm   = wv >> 1;
    const int wn   = wv & 1;
    const int lr   = lane & 15;
    const int ls   = lane >> 4;
    const int m0   = blockIdx.y * 128;
    const int n0   = blockIdx.x * 64;

    const unsigned short* wb6[6] = {
        wih + (size_t)n0 * HDIM,
        wih + (size_t)(HDIM + n0) * HDIM,
        wih + (size_t)(2 * HDIM + n0) * HDIM,
        ur  + (size_t)n0 * HDIM,
        uz  + (size_t)n0 * HDIM,
        un  + (size_t)n0 * HDIM
    };

    // staging chunk indices (weights): chunk c covers row c>>2, swizzled source slot
    const int wr  = tid >> 2;
    const int wsl = (tid & 3) ^ ((tid >> 3) & 3);

    f32x4 acc[4][4][2];
#pragma unroll
    for (int g = 0; g < 4; ++g)
#pragma unroll
        for (int mf = 0; mf < 4; ++mf)
#pragma unroll
            for (int nf = 0; nf < 2; ++nf)
                acc[g][mf][nf] = f32x4{0.f, 0.f, 0.f, 0.f};

    auto STAGE = [&](int bufi, int kt) {
        const int k0 = kt * 32;
        unsigned short* sb = &smem[bufi][0];
        // 6 weight tiles via global_load_lds w16 (linear LDS dest, pre-swizzled src)
#pragma unroll
        for (int mi = 0; mi < 6; ++mi) {
            const unsigned short* g = wb6[mi] + (size_t)wr * HDIM + k0 + wsl * 8;
            __builtin_amdgcn_global_load_lds(
                (const __attribute__((address_space(1))) void*)g,
                (__attribute__((address_space(3))) void*)(sb + 8192 + mi * 2048 + wv * 512),
                16, 0, 0);
        }
        // x/h bf16 tiles (4 loads/thread)
#pragma unroll
        for (int half = 0; half < 2; ++half) {
            const int c2 = half * 256 + tid;
            const int r2 = c2 >> 2;
            const int sl = (c2 & 3) ^ ((c2 >> 3) & 3);
            const unsigned short* gx = xb + (size_t)(m0 + r2) * HDIM + k0 + sl * 8;
            const unsigned short* gh = hb + (size_t)(m0 + r2) * HDIM + k0 + sl * 8;
            __builtin_amdgcn_global_load_lds(
                (const __attribute__((address_space(1))) void*)gx,
                (__attribute__((address_space(3))) void*)(sb + half * 2048 + wv * 512),
                16, 0, 0);
            __builtin_amdgcn_global_load_lds(
                (const __attribute__((address_space(1))) void*)gh,
                (__attribute__((address_space(3))) void*)(sb + 4096 + half * 2048 + wv * 512),
                16, 0, 0);
        }
    };

    auto COMPUTE = [&](int bufi) {
        const unsigned short* sb = &smem[bufi][0];
        const int sel = (lr >> 1) & 3;
        const int fo  = (ls ^ sel) << 3;
        bf16x8 ax[4], ah[4];
#pragma unroll
        for (int mf = 0; mf < 4; ++mf) {
            const int row = wm * 64 + mf * 16 + lr;
            ax[mf] = *(const bf16x8*)(sb + row * 32 + fo);
            ah[mf] = *(const bf16x8*)(sb + 4096 + row * 32 + fo);
        }
#pragma unroll
        for (int mi = 0; mi < 6; ++mi) {
            const unsigned short* wt = sb + 8192 + mi * 2048;
            bf16x8 b0 = *(const bf16x8*)(wt + (wn * 32 + lr) * 32 + fo);
            bf16x8 b1 = *(const bf16x8*)(wt + (wn * 32 + 16 + lr) * 32 + fo);
            const int g = (mi == 0 || mi == 3) ? 0 : (mi == 1 || mi == 4) ? 1 : (mi == 2) ? 2 : 3;
            const bf16x8* a = (mi < 3) ? ax : ah;
#pragma unroll
            for (int mf = 0; mf < 4; ++mf) {
                acc[g][mf][0] = __builtin_amdgcn_mfma_f32_16x16x32_bf16(a[mf], b0, acc[g][mf][0], 0, 0, 0);
                acc[g][mf][1] = __builtin_amdgcn_mfma_f32_16x16x32_bf16(a[mf], b1, acc[g][mf][1], 0, 0, 0);
            }
        }
    };

    // EXACT counted wait: STAGE issues 10 loads; with 10 leftover from the
    // previous tile, vmcnt(10) drains exactly those 10 (in-order retire)
    // and leaves all 10 fresh loads in flight across COMPUTE.
    auto WAITN = [&]() { asm volatile("s_waitcnt vmcnt(10)" ::: "memory"); };

    STAGE(0, 0);
#pragma unroll 1
    for (int kt = 0; kt < NT - 2; kt += 2) {
        STAGE(1, kt + 1); WAITN(); barrier_fence();
        COMPUTE(0);       barrier_fence();
        STAGE(0, kt + 2); WAITN(); barrier_fence();
        COMPUTE(1);       barrier_fence();
    }
    STAGE(1, NT - 1); WAITN(); barrier_fence();
    COMPUTE(0);       barrier_fence();
    asm volatile("s_waitcnt vmcnt(0) lgkmcnt(0)" ::: "memory");
    __builtin_amdgcn_s_barrier();
    asm volatile("" ::: "memory");
    COMPUTE(1);

    // epilogue: gates + output (C/D layout: col=lane&15, row=(lane>>4)*4+reg)
#pragma unroll
    for (int nf = 0; nf < 2; ++nf) {
        const int gc = n0 + wn * 32 + nf * 16 + lr;
        const float br  = bih[gc];
        const float bz  = bih[HDIM + gc];
        const float bnx = bih[2 * HDIM + gc];
        const float bn2 = bun[gc];
#pragma unroll
        for (int mf = 0; mf < 4; ++mf) {
#pragma unroll
            for (int rr = 0; rr < 4; ++rr) {
                const int gr = m0 + wm * 64 + mf * 16 + ls * 4 + rr;
                const float rv = 1.f / (1.f + __expf(-(acc[0][mf][nf][rr] + br)));
                const float zv = 1.f / (1.f + __expf(-(acc[1][mf][nf][rr] + bz)));
                const float nv = tanhf(acc[2][mf][nf][rr] + bnx + rv * (acc[3][mf][nf][rr] + bn2));
                const float hv = b2f(hb[(size_t)gr * HDIM + gc]);
                out[(size_t)gr * HDIM + gc] = (1.f - zv) * nv + zv * hv;
            }
        }
    }
}

// ---------- fallback (ws too small): R2's proven 4-wave fp32-staging kernel ----------
__global__ void __launch_bounds__(256, 2)
gru_fused_fb(const float* __restrict__ hg,
             const float* __restrict__ xg32, const float* __restrict__ hg32,
             const unsigned short* __restrict__ wih,
             const unsigned short* __restrict__ ur,
             const unsigned short* __restrict__ uz,
             const unsigned short* __restrict__ un,
             const float* __restrict__ bih, const float* __restrict__ bun,
             float* __restrict__ out) {
    __shared__ __align__(16) unsigned short smem[2][20480];
    const int tid  = threadIdx.x;
    const int lane = tid & 63;
    const int wv   = tid >> 6;
    const int wm   = wv >> 1;
    const int wn   = wv & 1;
    const int lr   = lane & 15;
    const int ls   = lane >> 4;
    const int m0   = blockIdx.y * 128;
    const int n0   = blockIdx.x * 64;

    const unsigned short* wb6[6] = {
        wih + (size_t)n0 * HDIM, wih + (size_t)(HDIM + n0) * HDIM,
        wih + (size_t)(2 * HDIM + n0) * HDIM, ur + (size_t)n0 * HDIM,
        uz + (size_t)n0 * HDIM, un + (size_t)n0 * HDIM
    };
    const int wr  = tid >> 2;
    const int wsl = (tid & 3) ^ ((tid >> 3) & 3);

    f32x4 acc[4][4][2];
#pragma unroll
    for (int g = 0; g < 4; ++g)
#pragma unroll
        for (int mf = 0; mf < 4; ++mf)
#pragma unroll
            for (int nf = 0; nf < 2; ++nf)
                acc[g][mf][nf] = f32x4{0.f, 0.f, 0.f, 0.f};

    auto STAGE = [&](int bufi, int kt) {
        const int k0 = kt * 32;
        unsigned short* sb = &smem[bufi][0];
        float4 fx[2][2], fh[2][2];
#pragma unroll
        for (int half = 0; half < 2; ++half) {
            const int c2 = half * 256 + tid;
            const int r2 = c2 >> 2;
            const int sl = c2 & 3;
            const float* gx = xg32 + (size_t)(m0 + r2) * HDIM + k0 + sl * 8;
            const float* gh = hg32 + (size_t)(m0 + r2) * HDIM + k0 + sl * 8;
            fx[half][0] = ((const float4*)gx)[0];
            fx[half][1] = ((const float4*)gx)[1];
            fh[half][0] = ((const float4*)gh)[0];
            fh[half][1] = ((const float4*)gh)[1];
        }
#pragma unroll
        for (int mi = 0; mi < 6; ++mi) {
            const unsigned short* g = wb6[mi] + (size_t)wr * HDIM + k0 + wsl * 8;
            __builtin_amdgcn_global_load_lds(
                (const __attribute__((address_space(1))) void*)g,
                (__attribute__((address_space(3))) void*)(sb + 8192 + mi * 2048 + wv * 512),
                16, 0, 0);
        }
#pragma unroll
        for (int half = 0; half < 2; ++half) {
            const int c2 = half * 256 + tid;
            const int r2 = c2 >> 2;
            const int sp = (c2 & 3) ^ ((c2 >> 3) & 3);
            u16x8 px, ph;
#pragma unroll
            for (int q = 0; q < 4; ++q) {
                px[q]     = f2b(fx[half][0][q]);
                px[q + 4] = f2b(fx[half][1][q]);
                ph[q]     = f2b(fh[half][0][q]);
                ph[q + 4] = f2b(fh[half][1][q]);
            }
            *(u16x8*)(sb + r2 * 32 + sp * 8)        = px;
            *(u16x8*)(sb + 4096 + r2 * 32 + sp * 8) = ph;
        }
    };
    auto COMPUTE = [&](int bufi) {
        const unsigned short* sb = &smem[bufi][0];
        const int sel = (lr >> 1) & 3;
        const int fo  = (ls ^ sel) << 3;
        bf16x8 ax[4], ah[4];
#pragma unroll
        for (int mf = 0; mf < 4; ++mf) {
            const int row = wm * 64 + mf * 16 + lr;
            ax[mf] = *(const bf16x8*)(sb + row * 32 + fo);
            ah[mf] = *(const bf16x8*)(sb + 4096 + row * 32 + fo);
        }
#pragma unroll
        for (int mi = 0; mi < 6; ++mi) {
            const unsigned short* wt = sb + 8192 + mi * 2048;
            bf16x8 b0 = *(const bf16x8*)(wt + (wn * 32 + lr) * 32 + fo);
            bf16x8 b1 = *(const bf16x8*)(wt + (wn * 32 + 16 + lr) * 32 + fo);
            const int g = (mi == 0 || mi == 3) ? 0 : (mi == 1 || mi == 4) ? 1 : (mi == 2) ? 2 : 3;
            const bf16x8* a = (mi < 3) ? ax : ah;
#pragma unroll
            for (int mf = 0; mf < 4; ++mf) {
                acc[g][mf][0] = __builtin_amdgcn_mfma_f32_16x16x32_bf16(a[mf], b0, acc[g][mf][0], 0, 0, 0);
                acc[g][mf][1] = __builtin_amdgcn_mfma_f32_16x16x32_bf16(a[mf], b1, acc[g][mf][1], 0, 0, 0);
            }
        }
    };
    auto WAITN = [&]() { asm volatile("s_waitcnt vmcnt(6) lgkmcnt(0)" ::: "memory"); };

    STAGE(0, 0);
#pragma unroll 1
    for (int kt = 0; kt < NT - 2; kt += 2) {
        STAGE(1, kt + 1); WAITN(); barrier_fence();
        COMPUTE(0);       barrier_fence();
        STAGE(0, kt + 2); WAITN(); barrier_fence();
        COMPUTE(1);       barrier_fence();
    }
    STAGE(1, NT - 1); WAITN(); barrier_fence();
    COMPUTE(0);       barrier_fence();
    asm volatile("s_waitcnt vmcnt(0) lgkmcnt(0)" ::: "memory");
    __builtin_amdgcn_s_barrier();
    asm volatile("" ::: "memory");
    COMPUTE(1);

#pragma unroll
    for (int nf = 0; nf < 2; ++nf) {
        const int gc = n0 + wn * 32 + nf * 16 + lr;
        const float br  = bih[gc];
        const float bz  = bih[HDIM + gc];
        const float bnx = bih[2 * HDIM + gc];
        const float bn2 = bun[gc];
#pragma unroll
        for (int mf = 0; mf < 4; ++mf) {
#pragma unroll
            for (int rr = 0; rr < 4; ++rr) {
                const int gr = m0 + wm * 64 + mf * 16 + ls * 4 + rr;
                const float rv = 1.f / (1.f + __expf(-(acc[0][mf][nf][rr] + br)));
                const float zv = 1.f / (1.f + __expf(-(acc[1][mf][nf][rr] + bz)));
                const float nv = tanhf(acc[2][mf][nf][rr] + bnx + rv * (acc[3][mf][nf][rr] + bn2));
                const float hv = hg[(size_t)gr * HDIM + gc];
                out[(size_t)gr * HDIM + gc] = (1.f - zv) * nv + zv * hv;
            }
        }
    }
}

extern "C" void kernel_launch(void* const* d_in, const int* in_sizes, int n_in,
                              void* d_out, int out_size, void* d_ws, size_t ws_size,
                              hipStream_t stream) {
    const float* x   = (const float*)d_in[0];
    const float* h   = (const float*)d_in[1];
    const float* Wih = (const float*)d_in[2];
    const float* bih = (const float*)d_in[3];
    const float* Ur  = (const float*)d_in[4];
    const float* Uz  = (const float*)d_in[5];
    const float* Un  = (const float*)d_in[6];
    const float* bun = (const float*)d_in[7];
    float* out = (float*)d_out;

    unsigned short* wsp  = (unsigned short*)d_ws;
    unsigned short* wihb = wsp;
    unsigned short* urb  = wihb + 3 * 1024 * 1024;
    unsigned short* uzb  = urb + 1024 * 1024;
    unsigned short* unb  = uzb + 1024 * 1024;
    unsigned short* xbb  = unb + 1024 * 1024;
    unsigned short* hbb  = xbb + 8 * 1024 * 1024;

    const bool big = ws_size >= 46137344ull;  // 44 MB

    cvt_all<<<big ? 22528 : 6144, 256, 0, stream>>>(
        x, h, Wih, Ur, Uz, Un, wihb, urb, uzb, unb, xbb, hbb);

    if (big) {
        dim3 grid(HDIM / 64, 8192 / 128);  // (16, 64), x-major dispatch
        gru8<<<grid, 256, 0, stream>>>(
            xbb, hbb, wihb, urb, uzb, unb, bih, bun, out);
    } else {
        dim3 grid(HDIM / 64, 8192 / 128);
        gru_fused_fb<<<grid, 256, 0, stream>>>(
            h, x, h, wihb, urb, uzb, unb, bih, bun, out);
    }
}